// Round 1
// baseline (23768.906 us; speedup 1.0000x reference)
//
#include <hip/hip_runtime.h>
#include <hip/hip_cooperative_groups.h>

namespace cg = cooperative_groups;

namespace {
constexpr int Bn = 64;    // batch
constexpr int Sn = 512;   // seq len
constexpr int Fn = 128;   // feature in/out
constexpr int Hn = 512;   // hidden
constexpr int NWG = 256;  // workgroups (1 per CU)
constexpr int NTHR = 256; // threads per WG
}

__device__ __forceinline__ float sigmoid_f(float v) {
    return 1.0f / (1.0f + __expf(-v));
}
__device__ __forceinline__ float tanh_f(float v) {
    v = fminf(fmaxf(v, -15.0f), 15.0f);
    const float e = __expf(-2.0f * v);
    return (1.0f - e) / (1.0f + e);
}

// Persistent LSTM. WG w owns hidden units j0=2w, 2w+1 (all 4 gates = 8 gate rows)
// and output feature f_out = w>>1 for half the batches. h ping-pongs in hbuf
// (layout [H][B]), c-state lives in LDS for the whole sequence.
__global__ __launch_bounds__(NTHR, 1)
void lstm_persist(const float* __restrict__ x,     // [B,S,F]
                  const float* __restrict__ Wih,   // [4H,F]
                  const float* __restrict__ Whh,   // [4H,H]
                  const float* __restrict__ bih,   // [4H]
                  const float* __restrict__ bhh,   // [4H]
                  const float* __restrict__ Wout,  // [F,H]
                  const float* __restrict__ bout,  // [F]
                  float* __restrict__ out,         // [B,S,F]
                  float* __restrict__ hbuf)        // 2 * H*B floats (ws)
{
    cg::grid_group grid = cg::this_grid();
    const int w = blockIdx.x;
    const int t = threadIdx.x;
    const int b = t & 63;                                   // lane-varying batch
    const int qu = __builtin_amdgcn_readfirstlane(t >> 6);  // wave-uniform K quarter

    __shared__ float hck[2][64][68];   // h chunk tiles, [k][b] layout (+pad)
    __shared__ float hcx[2][64][68];   // x chunk tiles, [b][k] layout (+pad)
    __shared__ float part[4][8][64];   // gate partials [q][lr][b]
    __shared__ float opart[4][64];     // out partials  [q][b]
    __shared__ float cst[128];         // c state [u][b]
    __shared__ float gbias[8];
    __shared__ float obias_s;

    const int j0 = w * 2;
    const int f_out = w >> 1;
    const int bbase = (w & 1) << 5;

    size_t wbase[8], xbase[8];
#pragma unroll
    for (int lr = 0; lr < 8; ++lr) {
        const int grow = j0 + (lr >> 2) + (lr & 3) * Hn;  // gate row: j + g*H
        wbase[lr] = (size_t)grow * Hn;
        xbase[lr] = (size_t)grow * Fn;
    }

    if (t < 128) cst[t] = 0.0f;
    if (t < 8) {
        const int grow = j0 + (t >> 2) + (t & 3) * Hn;
        gbias[t] = bih[grow] + bhh[grow];
    }
    if (t == 8) obias_s = bout[f_out];
    if (t < 128) hbuf[w * 128 + t] = 0.0f;  // zero h_{-1} (buffer 0), 256*128 = H*B

    grid.sync();

    const int lrow = t >> 2;        // x-loader row (batch)
    const int lcol = (t & 3) << 4;  // x-loader col base

    for (int k = 0; k <= Sn; ++k) {
        const float* __restrict__ hprev = hbuf + (size_t)(k & 1) * (Hn * Bn);
        float* __restrict__ hnext = hbuf + (size_t)((k + 1) & 1) * (Hn * Bn);
        const bool do_gates = (k < Sn);
        const bool do_out = (k >= 1);

        float acc[8];
#pragma unroll
        for (int lr = 0; lr < 8; ++lr) acc[lr] = 0.0f;
        float oacc = 0.0f;

        // h chunk c is 4096 contiguous floats in hprev ([H][B] layout): flat copy.
        auto load_h_chunk = [&](int c, int buf) {
            const float4* src = reinterpret_cast<const float4*>(hprev + (size_t)c * 4096);
#pragma unroll
            for (int i = 0; i < 4; ++i) {
                const int fi = t + 256 * i;          // float4 index 0..1023
                const int row = fi >> 4;             // k-in-chunk
                const int col = (fi & 15) << 2;      // b
                const float4 v = src[fi];
                *reinterpret_cast<float4*>(&hck[buf][row][col]) = v;
            }
        };
        auto load_x_chunk = [&](int c, int buf) {
            const float* src = x + (size_t)lrow * (Sn * Fn) + (size_t)k * Fn + (c - 8) * 64 + lcol;
            float4 v0 = reinterpret_cast<const float4*>(src)[0];
            float4 v1 = reinterpret_cast<const float4*>(src)[1];
            float4 v2 = reinterpret_cast<const float4*>(src)[2];
            float4 v3 = reinterpret_cast<const float4*>(src)[3];
            float* d = &hcx[buf][lrow][lcol];
            reinterpret_cast<float4*>(d)[0] = v0;
            reinterpret_cast<float4*>(d)[1] = v1;
            reinterpret_cast<float4*>(d)[2] = v2;
            reinterpret_cast<float4*>(d)[3] = v3;
        };
        auto compute_h_chunk = [&](int c, int buf) {
#pragma unroll
            for (int ii = 0; ii < 4; ++ii) {
                const int kl = (qu << 4) + (ii << 2);  // wave-uniform
                const int kg = (c << 6) + kl;          // wave-uniform -> s_load W
                const float h0 = hck[buf][kl + 0][b];
                const float h1 = hck[buf][kl + 1][b];
                const float h2 = hck[buf][kl + 2][b];
                const float h3 = hck[buf][kl + 3][b];
#pragma unroll
                for (int lr = 0; lr < 8; ++lr) {
                    const float4 wv = *reinterpret_cast<const float4*>(Whh + wbase[lr] + kg);
                    acc[lr] += wv.x * h0 + wv.y * h1 + wv.z * h2 + wv.w * h3;
                }
                if (do_out) {
                    const float4 wv = *reinterpret_cast<const float4*>(Wout + (size_t)f_out * Hn + kg);
                    oacc += wv.x * h0 + wv.y * h1 + wv.z * h2 + wv.w * h3;
                }
            }
        };
        auto compute_x_chunk = [&](int c, int buf) {
#pragma unroll
            for (int ii = 0; ii < 4; ++ii) {
                const int kl = (qu << 4) + (ii << 2);
                const int kx = ((c - 8) << 6) + kl;    // wave-uniform
                const float4 hv = *reinterpret_cast<const float4*>(&hcx[buf][b][kl]);
#pragma unroll
                for (int lr = 0; lr < 8; ++lr) {
                    const float4 wv = *reinterpret_cast<const float4*>(Wih + xbase[lr] + kx);
                    acc[lr] += wv.x * hv.x + wv.y * hv.y + wv.z * hv.z + wv.w * hv.w;
                }
            }
        };

        load_h_chunk(0, 0);
        __syncthreads();
        for (int c = 0; c < 8; ++c) {
            if (c < 7) load_h_chunk(c + 1, (c + 1) & 1);
            else if (do_gates) load_x_chunk(8, 0);
            compute_h_chunk(c, c & 1);
            __syncthreads();
        }
        if (do_gates) {
            load_x_chunk(9, 1);
            compute_x_chunk(8, 0);
            __syncthreads();
            compute_x_chunk(9, 1);
        }

#pragma unroll
        for (int lr = 0; lr < 8; ++lr) part[qu][lr][b] = acc[lr];
        opart[qu][b] = oacc;
        __syncthreads();

        if (do_gates && t < 128) {
            const int u = t >> 6;
            const int bb = t & 63;
            float s[4];
#pragma unroll
            for (int g = 0; g < 4; ++g) {
                const int lr = u * 4 + g;
                s[g] = part[0][lr][bb] + part[1][lr][bb] + part[2][lr][bb] +
                       part[3][lr][bb] + gbias[lr];
            }
            const float ig = sigmoid_f(s[0]);
            const float fg = sigmoid_f(s[1]);
            const float gg = tanh_f(s[2]);
            const float og = sigmoid_f(s[3]);
            const float cn = fg * cst[t] + ig * gg;
            cst[t] = cn;
            hnext[(size_t)(j0 + u) * Bn + bb] = og * tanh_f(cn);  // coalesced
        }
        if (do_out && t < 32) {
            const int bb = bbase + t;
            const float v = opart[0][bb] + opart[1][bb] + opart[2][bb] +
                            opart[3][bb] + obias_s;
            out[(size_t)bb * (Sn * Fn) + (size_t)(k - 1) * Fn + f_out] = v;
        }
        grid.sync();
    }
}

extern "C" void kernel_launch(void* const* d_in, const int* in_sizes, int n_in,
                              void* d_out, int out_size, void* d_ws, size_t ws_size,
                              hipStream_t stream) {
    const float* x    = (const float*)d_in[0];
    const float* Wih  = (const float*)d_in[1];
    const float* Whh  = (const float*)d_in[2];
    const float* bih  = (const float*)d_in[3];
    const float* bhh  = (const float*)d_in[4];
    const float* Wout = (const float*)d_in[5];
    const float* bout = (const float*)d_in[6];
    float* out  = (float*)d_out;
    float* hbuf = (float*)d_ws;  // needs 2*H*B*4 = 256 KB

    void* args[] = {(void*)&x, (void*)&Wih, (void*)&Whh, (void*)&bih, (void*)&bhh,
                    (void*)&Wout, (void*)&bout, (void*)&out, (void*)&hbuf};
    hipLaunchCooperativeKernel((void*)lstm_persist, dim3(NWG), dim3(NTHR), args, 0, stream);
}

// Round 4
// 10048.232 us; speedup vs baseline: 2.3655x; 2.3655x over previous
//
#include <hip/hip_runtime.h>

typedef float f32x4 __attribute__((ext_vector_type(4)));

namespace {
constexpr int Bn = 64, Sn = 512, Fn = 128, Hn = 512;
constexpr int NWG = 256, NTHR = 256;
constexpr int HXS = 644;    // LDS row stride (dwords), 16B-aligned
constexpr int RING0 = 1024; // ring base offset in floats (first 4 KB = barrier counters)
}

__device__ __forceinline__ float sigmoid_f(float v) {
    return 1.0f / (1.0f + __expf(-v));
}
__device__ __forceinline__ float tanh_f(float v) {
    v = fminf(fmaxf(v, -15.0f), 15.0f);
    const float e = __expf(-2.0f * v);
    return (1.0f - e) / (1.0f + e);
}

// Persistent LSTM, 1 WG/CU (VGPR-bound), PLAIN launch: grid == 256 == #CUs, so all
// WGs are co-resident; grid sync is a custom 2-level counter barrier (no acq/rel
// fences -> per-XCD L2 never invalidated; x/Wout stay L2-hot all 512 steps).
// WG w: rw=w>>3 owns hidden units 16rw..16rw+15 (64 gate rows) + out-features
// 4rw..4rw+3; bw=w&7 owns batches 8bw..8bw+7. Gate weights live in VGPRs
// (320/thread). h crosses XCDs via explicit sc0|sc1 loads/stores (L3 = coherence pt).
__global__ __launch_bounds__(NTHR, 1)
void lstm_persist(const float* __restrict__ x,     // [B,S,F]
                  const float* __restrict__ Wih,   // [4H,F]
                  const float* __restrict__ Whh,   // [4H,H]
                  const float* __restrict__ bih,   // [4H]
                  const float* __restrict__ bhh,   // [4H]
                  const float* __restrict__ Wout,  // [F,H]
                  const float* __restrict__ bout,  // [F]
                  float* __restrict__ out,         // [B,S,F]
                  float* __restrict__ ws)          // [counters 4KB][2][B][H] h ring
{
    const int w = blockIdx.x, t = threadIdx.x;
    const int bw = w & 7, rw = w >> 3;

    // gate-GEMM decomposition: K-octant q (80 wide), row-quad r4, batch-half b4
    const int q  = t >> 5;
    const int r4 = (t >> 1) & 15;
    const int b4 = t & 1;
    const int k0 = 80 * q;

    // out-projection decomposition (4 feats x 8 batches x 8 K-slices of 64)
    const int out_fi  = (t >> 1) & 3;
    const int out_bb  = (t >> 3) & 7;
    const int out_ksl = ((t >> 6) << 1) | (t & 1);

    __shared__ float hx[8][HXS];       // staged [h(512) | x(128)] per local batch
    __shared__ float part[8][64][9];   // gate partials [q][row][batch(+pad)]
    __shared__ float opart[4][8][9];   // out partials  [fi][batch][ksl(+pad)]
    __shared__ float gb[64];           // gate biases
    __shared__ float cst[16][9];       // c state [unit][batch(+pad)]
    __shared__ float bo[4];            // out biases

    // ---- one-time weight preload into registers: 4 rows x 20 quads (K=640) ----
    f32x4 wreg[4][20];
#pragma unroll
    for (int i = 0; i < 4; ++i) {
        const int r = 4 * r4 + i;                          // row in WG [0,64)
        const int G = (r >> 4) * Hn + rw * 16 + (r & 15);  // global gate row
#pragma unroll
        for (int j = 0; j < 20; ++j) {
            const int kk = k0 + 4 * j;
            if (kk < Hn) wreg[i][j] = *(const f32x4*)(Whh + (size_t)G * Hn + kk);
            else         wreg[i][j] = *(const f32x4*)(Wih + (size_t)G * Fn + (kk - Hn));
        }
    }

    if (t < 64) {
        const int G = (t >> 4) * Hn + rw * 16 + (t & 15);
        gb[t] = bih[G] + bhh[G];
    }
    if (t < 4) bo[t] = bout[rw * 4 + t];
    if (t < 128) cst[t >> 3][t & 7] = 0.0f;

    unsigned* const bar = (unsigned*)ws;  // root @0, group g @ 32*(g+1); memset by host
    float* const ring = ws + RING0;

    // ---- zero h_{-1} (ring slot 1): each WG zeroes exactly its owned cells ----
    if (t < 128) {
        const int ul = t & 15, bb = (t >> 4) & 7;
        float* hdst = ring + (size_t)(Bn * Hn) +
                      (size_t)(8 * bw + bb) * Hn + (16 * rw + ul);
        const float z = 0.0f;
        asm volatile("global_store_dword %0, %1, off sc0 sc1"
                     :: "v"(hdst), "v"(z) : "memory");
    }
    asm volatile("s_waitcnt vmcnt(0)" ::: "memory");
    __syncthreads();
    // ---- grid barrier, generation 1 (counters zeroed by 4 KB hipMemsetAsync) ----
    if (t == 0) {
        unsigned* gcnt = bar + 32 * ((w >> 4) + 1);
        const unsigned old = atomicAdd(gcnt, 1u);
        if (old == 15u) atomicAdd(bar, 1u);
        int guard = 0;
        while (__hip_atomic_load(bar, __ATOMIC_RELAXED,
                                 __HIP_MEMORY_SCOPE_AGENT) < 16u) {
            __builtin_amdgcn_s_sleep(1);
            if (++guard > 100000) break;
        }
    }
    __syncthreads();

    for (int k = 0; k <= Sn; ++k) {
        // ---- stage h_{k-1} (ring slot (k&1)^1) for OUR 8 batches, sc0|sc1 ----
        const int slot = (k & 1) ^ 1;
        const float* hsrc = ring + (size_t)slot * (Bn * Hn) + (size_t)bw * 8 * Hn;
        f32x4 v0, v1, v2, v3;
        {
            const float* p0 = hsrc + 4 * t;
            const float* p1 = p0 + 1024;
            const float* p2 = p0 + 2048;
            const float* p3 = p0 + 3072;
            asm volatile(
                "global_load_dwordx4 %0, %4, off sc0 sc1\n\t"
                "global_load_dwordx4 %1, %5, off sc0 sc1\n\t"
                "global_load_dwordx4 %2, %6, off sc0 sc1\n\t"
                "global_load_dwordx4 %3, %7, off sc0 sc1\n\t"
                "s_waitcnt vmcnt(0)"
                : "=&v"(v0), "=&v"(v1), "=&v"(v2), "=&v"(v3)
                : "v"(p0), "v"(p1), "v"(p2), "v"(p3));
        }
        {
            int fi = t;
            *(f32x4*)&hx[fi >> 7][(fi & 127) * 4] = v0;
            fi = t + 256;
            *(f32x4*)&hx[fi >> 7][(fi & 127) * 4] = v1;
            fi = t + 512;
            *(f32x4*)&hx[fi >> 7][(fi & 127) * 4] = v2;
            fi = t + 768;
            *(f32x4*)&hx[fi >> 7][(fi & 127) * 4] = v3;
        }
        if (k < Sn) {  // stage x[:,k,:] for our 8 batches (plain cached loads)
            const int bb = t >> 5, f4 = (t & 31) * 4;
            const f32x4 v = *(const f32x4*)(x + (size_t)(8 * bw + bb) * Sn * Fn +
                                            (size_t)k * Fn + f4);
            *(f32x4*)&hx[bb][Hn + f4] = v;
        }
        __syncthreads();

        // ---- gate GEMM: acc[4 rows][4 batches] over K-slice [k0,k0+80) ----
        if (k < Sn) {
            float acc[4][4];
#pragma unroll
            for (int i = 0; i < 4; ++i)
#pragma unroll
                for (int ib = 0; ib < 4; ++ib) acc[i][ib] = 0.0f;
#pragma unroll
            for (int j = 0; j < 20; ++j) {
                f32x4 hv[4];
#pragma unroll
                for (int ib = 0; ib < 4; ++ib)
                    hv[ib] = *(const f32x4*)&hx[4 * b4 + ib][k0 + 4 * j];
#pragma unroll
                for (int i = 0; i < 4; ++i)
#pragma unroll
                    for (int ib = 0; ib < 4; ++ib)
                        acc[i][ib] += wreg[i][j].x * hv[ib].x + wreg[i][j].y * hv[ib].y +
                                      wreg[i][j].z * hv[ib].z + wreg[i][j].w * hv[ib].w;
            }
#pragma unroll
            for (int i = 0; i < 4; ++i)
#pragma unroll
                for (int ib = 0; ib < 4; ++ib)
                    part[q][4 * r4 + i][4 * b4 + ib] = acc[i][ib];
        }

        // ---- pipelined out-projection for step k-1 (uses staged h_{k-1}) ----
        if (k >= 1) {
            const float* wo = Wout + (size_t)(rw * 4 + out_fi) * Hn + out_ksl * 64;
            const float* hrow = &hx[out_bb][out_ksl * 64];
            float oa = 0.0f;
#pragma unroll
            for (int jj = 0; jj < 16; ++jj) {
                const f32x4 wv = *(const f32x4*)(wo + 4 * jj);
                const f32x4 hv = *(const f32x4*)(hrow + 4 * jj);
                oa += wv.x * hv.x + wv.y * hv.y + wv.z * hv.z + wv.w * hv.w;
            }
            opart[out_fi][out_bb][out_ksl] = oa;
        }
        __syncthreads();

        // ---- cell update (t<128) + out finalize (t in [128,160)) ----
        if (k < Sn && t < 128) {
            const int ul = t & 15, bb = (t >> 4) & 7;
            float g4[4];
#pragma unroll
            for (int gate = 0; gate < 4; ++gate) {
                const int r = gate * 16 + ul;
                float s = gb[r];
#pragma unroll
                for (int qq = 0; qq < 8; ++qq) s += part[qq][r][bb];
                g4[gate] = s;
            }
            const float ig = sigmoid_f(g4[0]);
            const float fg = sigmoid_f(g4[1]);
            const float gg = tanh_f(g4[2]);
            const float og = sigmoid_f(g4[3]);
            const float cn = fg * cst[ul][bb] + ig * gg;
            cst[ul][bb] = cn;
            const float hn = og * tanh_f(cn);
            float* hdst = ring + (size_t)(k & 1) * (Bn * Hn) +
                          (size_t)(8 * bw + bb) * Hn + (16 * rw + ul);
            // write-through to the L3 coherence point
            asm volatile("global_store_dword %0, %1, off sc0 sc1"
                         :: "v"(hdst), "v"(hn) : "memory");
        } else if (k >= 1 && t >= 128 && t < 160) {
            const int fi = (t - 128) >> 3, bb = (t - 128) & 7;
            float s = bo[fi];
#pragma unroll
            for (int qq = 0; qq < 8; ++qq) s += opart[fi][bb][qq];
            out[(size_t)(8 * bw + bb) * Sn * Fn + (size_t)(k - 1) * Fn + rw * 4 + fi] = s;
        }

        // ---- fence-free 2-level grid barrier (generation counters) ----
        if (k < Sn) {
            asm volatile("s_waitcnt vmcnt(0)" ::: "memory");  // h stores are in L3
            __syncthreads();
            if (t == 0) {
                const unsigned gen = (unsigned)(k + 2);  // gen 1 was the init barrier
                unsigned* gcnt = bar + 32 * ((w >> 4) + 1);
                const unsigned old = atomicAdd(gcnt, 1u);
                if (old == 16u * gen - 1u) atomicAdd(bar, 1u);
                const unsigned target = 16u * gen;
                int guard = 0;
                while (__hip_atomic_load(bar, __ATOMIC_RELAXED,
                                         __HIP_MEMORY_SCOPE_AGENT) < target) {
                    __builtin_amdgcn_s_sleep(1);
                    if (++guard > 100000) break;  // fail loud (wrong data), never hang
                }
            }
            __syncthreads();
        }
    }
}

extern "C" void kernel_launch(void* const* d_in, const int* in_sizes, int n_in,
                              void* d_out, int out_size, void* d_ws, size_t ws_size,
                              hipStream_t stream) {
    (void)in_sizes; (void)n_in; (void)out_size; (void)ws_size;
    const float* x    = (const float*)d_in[0];
    const float* Wih  = (const float*)d_in[1];
    const float* Whh  = (const float*)d_in[2];
    const float* bih  = (const float*)d_in[3];
    const float* bhh  = (const float*)d_in[4];
    const float* Wout = (const float*)d_in[5];
    const float* bout = (const float*)d_in[6];
    float* out = (float*)d_out;
    float* wsp = (float*)d_ws;  // [4 KB counters][256 KB h ring]

    hipMemsetAsync(d_ws, 0, 4096, stream);  // barrier counters only

    lstm_persist<<<dim3(NWG), dim3(NTHR), 0, stream>>>(
        x, Wih, Whh, bih, bhh, Wout, bout, out, wsp);
}